// Round 7
// baseline (205.237 us; speedup 1.0000x reference)
//
#include <hip/hip_runtime.h>
#include <hip/hip_bf16.h>
#include <math.h>

#define EMB 64
#define HEADS 4
#define HC 256
#define EDGE_DIM 16
#define NEG_SLOPE 0.2f
#define LN_EPS 1e-5f
#define NCOLS 272   // 256 xw cols + 4 a_src + 4 a_dst + 8 pad

typedef __attribute__((ext_vector_type(8))) short short8;
typedef __attribute__((ext_vector_type(4))) float f32x4;

__device__ __forceinline__ float bflo(unsigned int u) { return __uint_as_float(u << 16); }
__device__ __forceinline__ float bfhi(unsigned int u) { return __uint_as_float(u & 0xffff0000u); }
__device__ __forceinline__ float bfu(unsigned short u) { return __uint_as_float((unsigned int)u << 16); }
__device__ __forceinline__ unsigned short bfb(float f) {
    __hip_bfloat16 h = __float2bfloat16(f);
    return *(unsigned short*)&h;
}
__device__ __forceinline__ unsigned int pack_bf2(float a, float b) {
    return (unsigned int)bfb(a) | ((unsigned int)bfb(b) << 16);
}

// prep: zero cnt; we_att; WpT[64][256] bf16 (transposed Wp); WxT[272][64] bf16
__global__ void k_prep(const float* __restrict__ W_edge, const float* __restrict__ att_edge,
                       float* __restrict__ we_att, const float* __restrict__ Wp,
                       unsigned short* __restrict__ WpT, const float* __restrict__ W,
                       const float* __restrict__ att_src, const float* __restrict__ att_dst,
                       unsigned short* __restrict__ WxT, int* __restrict__ cnt, int n) {
    int i = blockIdx.x * blockDim.x + threadIdx.x;
    if (i < n) cnt[i] = 0;
    if (i < EDGE_DIM * HEADS) {
        int d = i >> 2, h = i & 3;
        float acc = 0.0f;
#pragma unroll
        for (int c = 0; c < EMB; ++c)
            acc += W_edge[d * HC + h * EMB + c] * att_edge[h * EMB + c];
        we_att[d * HEADS + h] = acc;
    }
    if (i < HC * EMB) {
        int k = i >> 8, jj = i & 255;              // WpT[k][jj] = Wp[jj][k]
        WpT[i] = bfb(Wp[jj * EMB + k]);
    }
    if (i < NCOLS * EMB) {
        int c = i >> 6, k = i & 63;
        float v = 0.0f;
        if (c < HC) {
            v = W[k * HC + c];
        } else if (c < HC + 4) {
            int h = c - HC;
            float s = 0.0f;
#pragma unroll
            for (int j = 0; j < EMB; ++j) s += W[k * HC + h * EMB + j] * att_src[h * EMB + j];
            v = s;
        } else if (c < HC + 8) {
            int h = c - HC - 4;
            float s = 0.0f;
#pragma unroll
            for (int j = 0; j < EMB; ++j) s += W[k * HC + h * EMB + j] * att_dst[h * EMB + j];
            v = s;
        }
        WxT[i] = bfb(v);
    }
}

// ---- MFMA GEMM: [xw | a_src | a_dst] = x @ Wx ; 16 nodes/block, 4 waves ----
__global__ void __launch_bounds__(256)
k_xw_mfma(const float* __restrict__ x, const unsigned short* __restrict__ WxT,
          __hip_bfloat16* __restrict__ xwb, float* __restrict__ a_src,
          float* __restrict__ a_dst, int n) {
    int tid = threadIdx.x, lane = tid & 63, wv = tid >> 6;
    int g = lane >> 4, r16 = lane & 15;
    int mbase = blockIdx.x * 16;
    int row = mbase + r16;
    if (row >= n) row = n - 1;

    const float* xr = x + (size_t)row * EMB;
    short8 A[2];
#pragma unroll
    for (int kk = 0; kk < 2; ++kk) {
        float4 f0 = *(const float4*)(xr + kk * 32 + 8 * g);
        float4 f1 = *(const float4*)(xr + kk * 32 + 8 * g + 4);
        short8 a;
        a[0] = (short)bfb(f0.x); a[1] = (short)bfb(f0.y);
        a[2] = (short)bfb(f0.z); a[3] = (short)bfb(f0.w);
        a[4] = (short)bfb(f1.x); a[5] = (short)bfb(f1.y);
        a[6] = (short)bfb(f1.z); a[7] = (short)bfb(f1.w);
        A[kk] = a;
    }

    for (int t = wv; t <= 16; t += 4) {
        int col = t * 16 + r16;
        const unsigned short* bp = WxT + (size_t)col * EMB + 8 * g;
        short8 B0 = *(const short8*)(bp);
        short8 B1 = *(const short8*)(bp + 32);
        f32x4 acc = {0.f, 0.f, 0.f, 0.f};
        acc = __builtin_amdgcn_mfma_f32_16x16x32_bf16(A[0], B0, acc, 0, 0, 0);
        acc = __builtin_amdgcn_mfma_f32_16x16x32_bf16(A[1], B1, acc, 0, 0, 0);
        if (t < 16) {
#pragma unroll
            for (int r = 0; r < 4; ++r) {
                int node = mbase + 4 * g + r;
                if (node < n) xwb[(size_t)node * HC + col] = __float2bfloat16(acc[r]);
            }
        } else {
#pragma unroll
            for (int r = 0; r < 4; ++r) {
                int node = mbase + 4 * g + r;
                if (node < n) {
                    if (r16 < 4) a_src[node * HEADS + r16] = acc[r];
                    else if (r16 < 8) a_dst[node * HEADS + r16 - 4] = acc[r];
                }
            }
        }
    }
}

// ---- hist: rank atomic + full alpha math; aeb[e] = {ea01, ea23, ae01, ae23} ----
__global__ void k_hist(const int* __restrict__ ei, const float* __restrict__ edge_attr,
                       const float* __restrict__ we_att, const float* __restrict__ a_src,
                       const float* __restrict__ a_dst, int* __restrict__ cnt,
                       int* __restrict__ rank, uint4* __restrict__ aeb, int E) {
    __shared__ float wa[EDGE_DIM * HEADS];
    if (threadIdx.x < EDGE_DIM * HEADS) wa[threadIdx.x] = we_att[threadIdx.x];
    __syncthreads();
    int e = blockIdx.x * blockDim.x + threadIdx.x;
    if (e >= E) return;
    int s = ei[e], d = ei[E + e];
    const float4* ea4 = (const float4*)(edge_attr + (size_t)e * EDGE_DIM);
    float ae[HEADS] = {0.f, 0.f, 0.f, 0.f};
#pragma unroll
    for (int q = 0; q < 4; ++q) {
        float4 v4 = ea4[q];
        const float* vp = (const float*)&v4;
#pragma unroll
        for (int r = 0; r < 4; ++r) {
            float v = vp[r];
            int dd = q * 4 + r;
#pragma unroll
            for (int h = 0; h < HEADS; ++h) ae[h] += v * wa[dd * HEADS + h];
        }
    }
    float4 as4 = *(const float4*)(a_src + (size_t)s * HEADS);
    float4 ad4 = *(const float4*)(a_dst + (size_t)d * HEADS);
    const float* asp = (const float*)&as4;
    const float* adp = (const float*)&ad4;
    float ea[HEADS];
#pragma unroll
    for (int h = 0; h < HEADS; ++h) {
        float al = asp[h] + adp[h] + ae[h];
        al = al >= 0.0f ? al : NEG_SLOPE * al;
        ea[h] = __expf(al);          // no max-subtraction needed: |al| < ~8
    }
    rank[e] = atomicAdd(&cnt[d], 1);
    uint4 ab;
    ab.x = pack_bf2(ea[0], ea[1]);
    ab.y = pack_bf2(ea[2], ea[3]);
    ab.z = pack_bf2(ae[0], ae[1]);
    ab.w = pack_bf2(ae[2], ae[3]);
    aeb[e] = ab;
}

// ---------------- 3-dispatch exclusive scan over cnt[n] ----------------
__global__ void k_scan1(const int* __restrict__ cnt, int* __restrict__ tmp,
                        int* __restrict__ bsum, int n) {
    __shared__ int s[256];
    int i = blockIdx.x * 256 + threadIdx.x;
    int v = (i < n) ? cnt[i] : 0;
    s[threadIdx.x] = v;
    __syncthreads();
    for (int off = 1; off < 256; off <<= 1) {
        int t = (threadIdx.x >= off) ? s[threadIdx.x - off] : 0;
        __syncthreads();
        s[threadIdx.x] += t;
        __syncthreads();
    }
    if (i < n) tmp[i] = s[threadIdx.x];
    if (threadIdx.x == 255) bsum[blockIdx.x] = s[255];
}

__global__ void k_scan2(int* __restrict__ bsum, int nb) {
    __shared__ int s[256];
    int v = (threadIdx.x < nb) ? bsum[threadIdx.x] : 0;
    s[threadIdx.x] = v;
    __syncthreads();
    for (int off = 1; off < 256; off <<= 1) {
        int t = (threadIdx.x >= off) ? s[threadIdx.x - off] : 0;
        __syncthreads();
        s[threadIdx.x] += t;
        __syncthreads();
    }
    if (threadIdx.x < nb) bsum[threadIdx.x] = s[threadIdx.x] - v; // exclusive
}

__global__ void k_scan3(const int* __restrict__ tmp, const int* __restrict__ cnt,
                        const int* __restrict__ bsum, int* __restrict__ row_start, int n) {
    int i = blockIdx.x * 256 + threadIdx.x;
    if (i < n) row_start[i] = tmp[i] - cnt[i] + bsum[blockIdx.x];
}

// ---- scatter: pure permute into 32B CSR records ----
// record words: [0]=src [1]=pad [2]=ea01 [3]=ae01 [4]=ea23 [5]=ae23 [6,7]=pad
__global__ void k_scatter(const int* __restrict__ ei, const uint4* __restrict__ aeb,
                          const int* __restrict__ row_start, const int* __restrict__ rank,
                          unsigned int* __restrict__ recp, int E) {
    int e = blockIdx.x * blockDim.x + threadIdx.x;
    if (e >= E) return;
    int s = ei[e], d = ei[E + e];
    uint4 ab = aeb[e];
    int pos = row_start[d] + rank[e];
    size_t off = (size_t)pos * 8;
    uint4 w0;
    w0.x = (unsigned int)s;
    w0.y = 0u;
    w0.z = ab.x;   // ea01
    w0.w = ab.z;   // ae01
    *(uint4*)(recp + off) = w0;
    uint2 w1;
    w1.x = ab.y;   // ea23
    w1.y = ab.w;   // ae23
    *(uint2*)(recp + off + 4) = w1;
}

// ------- fused gather + softmax + aggregate + MFMA proj + LN: 4 nodes/block -------
#define PROC2(P, R)                                                       \
    {                                                                     \
        float a = hodd ? bfhi((P).x) : bflo((P).x);                       \
        float ae = hodd ? bfhi((P).y) : bflo((P).y);                      \
        dn += a; aeS += ae;                                               \
        acc0 += a * bfu((R).x); acc1 += a * bfu((R).y);                   \
        acc2 += a * bfu((R).z); acc3 += a * bfu((R).w);                   \
    }

__global__ void __launch_bounds__(256)
k_gather_out(const int* __restrict__ row_start, const int* __restrict__ cnt,
             const unsigned int* __restrict__ recp,
             const float* __restrict__ a_src, const float* __restrict__ a_dst,
             const __hip_bfloat16* __restrict__ xwb, const float* __restrict__ x,
             const float* __restrict__ bias, const unsigned short* __restrict__ WpT,
             const float* __restrict__ bp, const float* __restrict__ gamma,
             const float* __restrict__ beta, float* __restrict__ out, int n) {
    int tid = threadIdx.x, lane = tid & 63, wv = tid >> 6;
    int node = blockIdx.x * 4 + wv;
    bool valid = node < n;
    int nodeC = valid ? node : n - 1;
    int h4 = lane >> 4;
    bool hodd = (h4 & 1);

    __shared__ __align__(16) unsigned short gbf[4][272];  // bf16 g, pad 16 for banks
    __shared__ float pC[4][66];                            // proj result [node][ch]

    const unsigned short* xwu = (const unsigned short*)xwb;

    int rs = row_start[nodeC];
    int dg = valid ? cnt[nodeC] : 0;

    // hoisted self-node loads
    float as = a_src[nodeC * HEADS + h4];
    float ad = a_dst[nodeC * HEADS + h4];
    ushort4 sr = *(const ushort4*)(xwu + (size_t)nodeC * HC + (lane << 2));
    float4 bv = *(const float4*)(bias + (lane << 2));

    float acc0 = 0.f, acc1 = 0.f, acc2 = 0.f, acc3 = 0.f;
    float dn = 0.f, aeS = 0.f;

    const unsigned int* rp = recp + (size_t)rs * 8;
    const unsigned int* rp2 = rp + 2 + (h4 & 2);   // per-lane head pair address
    int j = 0;
    for (; j + 4 <= dg; j += 4, rp += 32, rp2 += 32) {
        unsigned s0 = rp[0], s1 = rp[8], s2 = rp[16], s3 = rp[24];
        uint2 P0 = *(const uint2*)(rp2);
        uint2 P1 = *(const uint2*)(rp2 + 8);
        uint2 P2 = *(const uint2*)(rp2 + 16);
        uint2 P3 = *(const uint2*)(rp2 + 24);
        ushort4 r0 = *(const ushort4*)(xwu + (size_t)s0 * HC + (lane << 2));
        ushort4 r1 = *(const ushort4*)(xwu + (size_t)s1 * HC + (lane << 2));
        ushort4 r2 = *(const ushort4*)(xwu + (size_t)s2 * HC + (lane << 2));
        ushort4 r3 = *(const ushort4*)(xwu + (size_t)s3 * HC + (lane << 2));
        PROC2(P0, r0)
        PROC2(P1, r1)
        PROC2(P2, r2)
        PROC2(P3, r3)
    }
    for (; j < dg; ++j, rp += 8, rp2 += 8) {
        unsigned s0 = rp[0];
        uint2 P = *(const uint2*)(rp2);
        ushort4 r = *(const ushort4*)(xwu + (size_t)s0 * HC + (lane << 2));
        PROC2(P, r)
    }

    // self-loop + normalize + bias -> bf16 g in LDS
    float cf = fmaxf((float)dg, 1.0f);
    float al = as + ad + aeS / cf;
    al = al >= 0.f ? al : NEG_SLOPE * al;
    float el = __expf(al);
    float inv = 1.0f / (dn + el);
    ushort4 gv;
    gv.x = bfb((acc0 + el * bfu(sr.x)) * inv + bv.x);
    gv.y = bfb((acc1 + el * bfu(sr.y)) * inv + bv.y);
    gv.z = bfb((acc2 + el * bfu(sr.z)) * inv + bv.z);
    gv.w = bfb((acc3 + el * bfu(sr.w)) * inv + bv.w);
    *(ushort4*)&gbf[wv][lane << 2] = gv;
    __syncthreads();

    // MFMA projection: wave wv computes col tile wv (16 cols) of g(4x256) @ Wp(256x64)
    {
        int g = lane >> 4, r16 = lane & 15;
        const unsigned short* wp = WpT + (size_t)(wv * 16 + r16) * HC + 8 * g;
        const unsigned short* ga = &gbf[r16 & 3][8 * g];
        f32x4 pacc = {0.f, 0.f, 0.f, 0.f};
#pragma unroll
        for (int kk = 0; kk < 8; ++kk) {
            short8 Af = *(const short8*)(ga + kk * 32);
            short8 Bf = *(const short8*)(wp + kk * 32);
            pacc = __builtin_amdgcn_mfma_f32_16x16x32_bf16(Af, Bf, pacc, 0, 0, 0);
        }
        if (g == 0) {
#pragma unroll
            for (int m = 0; m < 4; ++m) pC[m][wv * 16 + r16] = pacc[m];
        }
    }
    __syncthreads();

    // epilogue: wave wv -> node wv; lane = channel
    float p = pC[wv][lane] + bp[lane];
    float elv = p > 0.f ? p : expm1f(p);
    float xv = valid ? x[(size_t)node * EMB + lane] : 0.f;
    float hv = xv + elv;
    float s1 = hv, s2 = hv * hv;
    for (int off = 32; off > 0; off >>= 1) {
        s1 += __shfl_xor(s1, off);
        s2 += __shfl_xor(s2, off);
    }
    float mu = s1 * (1.0f / EMB);
    float var = s2 * (1.0f / EMB) - mu * mu;
    if (valid)
        out[(size_t)node * EMB + lane] = (hv - mu) * rsqrtf(var + LN_EPS) * gamma[lane] + beta[lane];
}

extern "C" void kernel_launch(void* const* d_in, const int* in_sizes, int n_in,
                              void* d_out, int out_size, void* d_ws, size_t ws_size,
                              hipStream_t stream) {
    const float* x        = (const float*)d_in[0];
    const int*   ei       = (const int*)d_in[1];
    const float* edge_attr= (const float*)d_in[2];
    const float* W        = (const float*)d_in[3];
    const float* W_edge   = (const float*)d_in[4];
    const float* att_src  = (const float*)d_in[5];
    const float* att_dst  = (const float*)d_in[6];
    const float* att_edge = (const float*)d_in[7];
    const float* bias     = (const float*)d_in[8];
    const float* Wp       = (const float*)d_in[9];
    const float* bp       = (const float*)d_in[10];
    const float* gamma    = (const float*)d_in[11];
    const float* beta     = (const float*)d_in[12];
    float* out = (float*)d_out;

    int n = in_sizes[0] / EMB;
    int E = in_sizes[1] / 2;
    int nb = (n + 255) / 256;

    float* ws = (float*)d_ws;
    float* a_src       = ws; ws += (size_t)n * HEADS;
    float* a_dst       = ws; ws += (size_t)n * HEADS;
    float* we_att      = ws; ws += EDGE_DIM * HEADS;
    __hip_bfloat16* xwb = (__hip_bfloat16*)ws; ws += (size_t)n * HC / 2;
    unsigned int* recp = (unsigned int*)ws; ws += (size_t)E * 8;    // 32B/edge
    uint4* aeb         = (uint4*)ws; ws += (size_t)E * 4;           // 16B/edge
    unsigned short* WpT = (unsigned short*)ws; ws += HC * EMB / 2;
    unsigned short* WxT = (unsigned short*)ws; ws += NCOLS * EMB / 2;
    int* iw = (int*)ws;
    int* cnt       = iw; iw += n;
    int* rank      = iw; iw += E;
    int* row_start = iw; iw += n;
    int* tmp       = iw; iw += n;
    int* bsum      = iw; iw += 256;

    const int tb = 256;
    hipLaunchKernelGGL(k_prep, dim3((n + tb - 1) / tb), dim3(tb), 0, stream,
                       W_edge, att_edge, we_att, Wp, WpT, W, att_src, att_dst, WxT, cnt, n);
    hipLaunchKernelGGL(k_xw_mfma, dim3((n + 15) / 16), dim3(tb), 0, stream,
                       x, WxT, xwb, a_src, a_dst, n);
    hipLaunchKernelGGL(k_hist, dim3((E + tb - 1) / tb), dim3(tb), 0, stream,
                       ei, edge_attr, we_att, a_src, a_dst, cnt, rank, aeb, E);
    hipLaunchKernelGGL(k_scan1, dim3(nb), dim3(tb), 0, stream, cnt, tmp, bsum, n);
    hipLaunchKernelGGL(k_scan2, dim3(1), dim3(tb), 0, stream, bsum, nb);
    hipLaunchKernelGGL(k_scan3, dim3(nb), dim3(tb), 0, stream, tmp, cnt, bsum, row_start, n);
    hipLaunchKernelGGL(k_scatter, dim3((E + tb - 1) / tb), dim3(tb), 0, stream,
                       ei, aeb, row_start, rank, recp, E);
    hipLaunchKernelGGL(k_gather_out, dim3((n + 3) / 4), dim3(tb), 0, stream,
                       row_start, cnt, recp, a_src, a_dst, xwb, x, bias, WpT, bp,
                       gamma, beta, out, n);
}